// Round 5
// baseline (206.153 us; speedup 1.0000x reference)
//
#include <hip/hip_runtime.h>
#include <stdint.h>

#define Bn 4096
#define Mn 8192
#define Fn 256
#define HIDn 256
#define Cn 64
#define KY 8          // K-split of M dimension
#define MCH (Mn / KY) // 1024 m per block
#define NIT (MCH / 64)// 16 iters

typedef float f32x4 __attribute__((ext_vector_type(4)));
typedef short s16x8 __attribute__((ext_vector_type(8)));

__device__ __forceinline__ uint16_t f2bf(float f) {
    union { float f; uint32_t u; } v; v.f = f;
    uint32_t r = v.u + 0x7FFFu + ((v.u >> 16) & 1u);
    return (uint16_t)(r >> 16);
}

// XOR swizzle for LDS tiles with 128B rows: flips bits 4-6 with row&7 (bits 7-9). Involution.
__device__ __forceinline__ uint32_t swz(uint32_t o) { return o ^ (((o >> 7) & 7u) << 4); }

__device__ __forceinline__ void glds16(const char* g, char* l) {
    __builtin_amdgcn_global_load_lds(
        (const __attribute__((address_space(1))) void*)g,
        (__attribute__((address_space(3))) void*)l, 16, 0, 0);
}

// ---------------------------------------------------------------------------
// Fused prep kernel, role-switched by blockIdx.x:
//  [0, 2048)    : maskpack via ballot — mask f32 (128 MB stream) -> 4 MB bitmask
//  [2048, 5120) : prep_xy — x[h][b], y[h][m], self_bf16
//  [5120, 7168) : tn — neighTg tiled+pre-swizzled bf16 transpose
//  [7168, 8320) : prep_w — enc_wT / out_wT bf16 transposes
__global__ __launch_bounds__(256) void k_prep_all(
    const float* __restrict__ selff, const float* __restrict__ neigh,
    const float* __restrict__ mask, const float* __restrict__ a,
    const float* __restrict__ enc_w, const float* __restrict__ out_w,
    float* __restrict__ x, float* __restrict__ y, uint16_t* __restrict__ self_bf,
    char* __restrict__ neighTg, uint16_t* __restrict__ enc_wT, uint16_t* __restrict__ out_wT,
    uint64_t* __restrict__ bitmask)
{
    __shared__ float tl[32][33];
    const int bid = blockIdx.x;
    if (bid < 2048) {
        // Each wave packs 4096 consecutive floats: lane reads 1 f32 (coalesced
        // 256 B / instruction), ballot packs the 64 bits, lane 0 stores u64.
        const int wid = threadIdx.x >> 6, l = threadIdx.x & 63;
        const size_t base = ((size_t)bid * 4 + wid) * 4096;   // float index
        const float* mp = mask + base + l;
        uint64_t* ob = bitmask + base / 64;
        #pragma unroll 1
        for (int i = 0; i < 64; i += 4) {
            const float v0 = mp[(i + 0) * 64];
            const float v1 = mp[(i + 1) * 64];
            const float v2 = mp[(i + 2) * 64];
            const float v3 = mp[(i + 3) * 64];
            const uint64_t q0 = __ballot(v0 > 0.f);
            const uint64_t q1 = __ballot(v1 > 0.f);
            const uint64_t q2 = __ballot(v2 > 0.f);
            const uint64_t q3 = __ballot(v3 > 0.f);
            if (l == 0) { ob[i] = q0; ob[i + 1] = q1; ob[i + 2] = q2; ob[i + 3] = q3; }
        }
    } else if (bid < 5120) {
        const int w = threadIdx.x >> 6, l = threadIdx.x & 63;
        const int r = (bid - 2048) * 4 + w;           // 0..B+M-1
        const bool is_self = (r < Bn);
        const float* row = is_self ? (selff + (size_t)r * Fn) : (neigh + (size_t)(r - Bn) * Fn);
        const int aoff = is_self ? 0 : Fn;
        const float4 v  = *(const float4*)(row + l * 4);
        const float4 c0 = *(const float4*)(a + aoff + l * 4);
        const float4 c1 = *(const float4*)(a + 2 * Fn + aoff + l * 4);
        float d0 = v.x * c0.x + v.y * c0.y + v.z * c0.z + v.w * c0.w;
        float d1 = v.x * c1.x + v.y * c1.y + v.z * c1.z + v.w * c1.w;
        #pragma unroll
        for (int s = 32; s > 0; s >>= 1) { d0 += __shfl_xor(d0, s); d1 += __shfl_xor(d1, s); }
        if (is_self) {
            uint2 pk;
            pk.x = (uint32_t)f2bf(v.x) | ((uint32_t)f2bf(v.y) << 16);
            pk.y = (uint32_t)f2bf(v.z) | ((uint32_t)f2bf(v.w) << 16);
            *(uint2*)(self_bf + (size_t)r * Fn + l * 4) = pk;
            if (l == 0) { x[r] = d0; x[Bn + r] = d1; }
        } else {
            const int m = r - Bn;
            if (l == 0) { y[m] = d0; y[Mn + m] = d1; }
        }
    } else if (bid < 7168) {
        const int bid3 = bid - 5120;
        const int tx = threadIdx.x & 31, ty = threadIdx.x >> 5;
        const int m0 = (bid3 & 255) * 32, f0 = (bid3 >> 8) * 32;
        #pragma unroll
        for (int i = 0; i < 4; ++i)
            tl[ty + 8 * i][tx] = neigh[(size_t)(m0 + ty + 8 * i) * Fn + f0 + tx];
        __syncthreads();
        #pragma unroll
        for (int i = 0; i < 4; ++i) {
            const int f = f0 + ty + 8 * i;
            const int m = m0 + tx;
            const uint32_t o = (uint32_t)(f * 128 + (m & 63) * 2);
            *(uint16_t*)(neighTg + (size_t)(m >> 6) * 32768 + swz(o)) = f2bf(tl[tx][ty + 8 * i]);
        }
    } else {
        const int tid = (bid - 7168) * 256 + threadIdx.x;
        if (tid < 2 * HIDn * 512) {
            const int h = tid >> 17;
            const int rr = tid & 131071;
            const int n = rr >> 9, k = rr & 511;
            enc_wT[tid] = f2bf(enc_w[(size_t)h * 512 * HIDn + (size_t)k * HIDn + n]);
        } else {
            const int rr = tid - 2 * HIDn * 512;
            const int n = rr >> 9, k = rr & 511;
            out_wT[rr] = f2bf(out_w[(size_t)k * Cn + n]);
        }
    }
}

// ---------------------------------------------------------------------------
// Main fused kernel. 80 KB LDS -> 2 blocks/CU (4 waves/SIMD). Single-buffered
// P with a 2-barrier scheme (A-frags hoisted to regs before barrier 1);
// double-buffered B via global_load_lds with counted vmcnt(5) drain.
__global__ __launch_bounds__(512, 4) void k_main(
    const uint8_t* __restrict__ bitb, const float* __restrict__ x, const float* __restrict__ y,
    const char* __restrict__ neighTg, float* __restrict__ Upart, float* __restrict__ Z4)
{
    __shared__ __align__(16) uint16_t ldsB[2][Fn * 64];   // 2 x 32KB, [f][m] swizzled
    __shared__ __align__(16) uint16_t ldsP[2 * 64 * 64];  // 16KB, [h][b][m] swizzled (single buf)
    const int t = threadIdx.x;
    const int w = t >> 6, l = t & 63;
    const int b0 = blockIdx.x * 64;
    const int ky = blockIdx.y;
    const int tile0 = ky * NIT;

    const int pb = t >> 3;          // P-build row
    const int pm = (t & 7) * 8;     // 8 consecutive m's
    const float x0 = x[b0 + pb];
    const float x1 = x[Bn + b0 + pb];
    float z0 = 0.f, z1 = 0.f;

    const int hw = w >> 2;          // head of this wave
    const int n0 = (w & 3) * 64;    // F-column block of this wave

    f32x4 acc[4][4];
    #pragma unroll
    for (int i = 0; i < 4; ++i)
        #pragma unroll
        for (int j = 0; j < 4; ++j)
            acc[i][j] = (f32x4){0.f, 0.f, 0.f, 0.f};

    const uint8_t* bp = bitb + (size_t)(b0 + pb) * (Mn / 8) + ky * (MCH / 8) + (t & 7);
    const float* y0p = y + ky * MCH + pm;
    const float* y1p = y + Mn + ky * MCH + pm;
    const uint32_t pwo = swz((uint32_t)(pb * 128 + pm * 2));
    const uint32_t gchunk = (uint32_t)(w * 4096);

    auto stage = [&](int kt, int buf) {
        const char* gb = neighTg + (size_t)(tile0 + kt) * 32768 + gchunk + (uint32_t)(l * 16);
        char* lb = (char*)ldsB[buf] + gchunk;
        #pragma unroll
        for (int c = 0; c < 4; ++c)
            glds16(gb + c * 1024, lb + c * 1024);
    };
    auto loadmy = [&](int kt, float4& a0, float4& a1, float4& b0_, float4& b1_, uint32_t& bt) {
        const int mo = kt * 64;
        a0 = *(const float4*)(y0p + mo);  a1 = *(const float4*)(y0p + mo + 4);
        b0_ = *(const float4*)(y1p + mo); b1_ = *(const float4*)(y1p + mo + 4);
        bt = bp[kt * 8];
    };
    auto buildP = [&](const float4& a0, const float4& a1, const float4& b0_, const float4& b1_, uint32_t bt) {
        float yv0[8] = {a0.x, a0.y, a0.z, a0.w, a1.x, a1.y, a1.z, a1.w};
        float yv1[8] = {b0_.x, b0_.y, b0_.z, b0_.w, b1_.x, b1_.y, b1_.z, b1_.w};
        uint16_t p0[8], p1[8];
        #pragma unroll
        for (int j = 0; j < 8; ++j) {
            const bool on = (bt >> j) & 1;
            float t0 = x0 + yv0[j];
            float s0 = fmaxf(t0, 0.2f * t0);
            float e0 = on ? __expf(s0) : 0.f;
            z0 += e0; p0[j] = f2bf(e0);
            float t1 = x1 + yv1[j];
            float s1 = fmaxf(t1, 0.2f * t1);
            float e1 = on ? __expf(s1) : 0.f;
            z1 += e1; p1[j] = f2bf(e1);
        }
        uint4 q0, q1;
        q0.x = p0[0] | ((uint32_t)p0[1] << 16); q0.y = p0[2] | ((uint32_t)p0[3] << 16);
        q0.z = p0[4] | ((uint32_t)p0[5] << 16); q0.w = p0[6] | ((uint32_t)p0[7] << 16);
        q1.x = p1[0] | ((uint32_t)p1[1] << 16); q1.y = p1[2] | ((uint32_t)p1[3] << 16);
        q1.z = p1[4] | ((uint32_t)p1[5] << 16); q1.w = p1[6] | ((uint32_t)p1[7] << 16);
        char* pw = (char*)ldsP;
        *(uint4*)(pw + pwo) = q0;
        *(uint4*)(pw + 8192 + pwo) = q1;
    };
    auto read_af = [&](int kk, s16x8* af) {
        const char* pA = (const char*)ldsP + hw * 8192;
        const uint32_t kb = (uint32_t)((kk * 32 + (l >> 4) * 8) * 2);
        #pragma unroll
        for (int i = 0; i < 4; ++i) {
            const uint32_t ar = (uint32_t)(i * 16 + (l & 15));
            af[i] = *(const s16x8*)(pA + swz(ar * 128 + kb));
        }
    };
    auto mfma_kk = [&](int buf, int kk, const s16x8* af) {
        const char* pB = (const char*)ldsB[buf];
        const uint32_t kb = (uint32_t)((kk * 32 + (l >> 4) * 8) * 2);
        s16x8 bfr[4];
        #pragma unroll
        for (int j = 0; j < 4; ++j) {
            const uint32_t br = (uint32_t)(n0 + j * 16 + (l & 15));
            bfr[j] = *(const s16x8*)(pB + swz(br * 128 + kb));
        }
        __builtin_amdgcn_s_setprio(1);
        #pragma unroll
        for (int i = 0; i < 4; ++i)
            #pragma unroll
            for (int j = 0; j < 4; ++j)
                acc[i][j] = __builtin_amdgcn_mfma_f32_16x16x32_bf16(af[i], bfr[j], acc[i][j], 0, 0, 0);
        __builtin_amdgcn_s_setprio(0);
    };

    // ---- prologue: P(0) built; B(0) staged; y(1)/bit(1) prefetched
    float4 ta0, ta1, tb0, tb1; uint32_t tbt;
    loadmy(0, ta0, ta1, tb0, tb1, tbt);     // 5 vmem
    stage(0, 0);                            // 4 glds
    buildP(ta0, ta1, tb0, tb1, tbt);        // waits y(0) only (vmcnt(4))
    float4 ca0, ca1, cb0, cb1; uint32_t cbt;
    loadmy(1, ca0, ca1, cb0, cb1, cbt);     // 5 vmem -> outstanding [g0:4][y1:5]
    asm volatile("s_waitcnt lgkmcnt(0)" ::: "memory");
    asm volatile("s_waitcnt vmcnt(5)" ::: "memory");   // drain g0, keep y1
    __builtin_amdgcn_s_barrier();

    // ---- main loop: kt = 0..13 full body; 14 peeled (no prefetch); 15 epilogue
    for (int kt = 0; kt < 14; ++kt) {
        const int cur = kt & 1, nxt = cur ^ 1;
        stage(kt + 1, nxt);                 // 4 glds
        s16x8 af0[4], af1[4];
        read_af(0, af0); read_af(1, af1);   // 8 ds_reads: A(kt) -> regs
        asm volatile("s_waitcnt lgkmcnt(0)" ::: "memory");
        __builtin_amdgcn_sched_barrier(0);
        __builtin_amdgcn_s_barrier();       // all waves hold A(kt); P writable
        mfma_kk(cur, 0, af0);
        buildP(ca0, ca1, cb0, cb1, cbt);    // P(kt+1); waits y(kt+1) via vmcnt(4)
        float4 na0, na1, nb0, nb1; uint32_t nbt;
        loadmy(kt + 2, na0, na1, nb0, nb1, nbt);  // 5 vmem
        mfma_kk(cur, 1, af1);
        ca0 = na0; ca1 = na1; cb0 = nb0; cb1 = nb1; cbt = nbt;
        asm volatile("s_waitcnt lgkmcnt(0)" ::: "memory");
        asm volatile("s_waitcnt vmcnt(5)" ::: "memory");  // drain g(kt+1), keep y(kt+2)
        __builtin_amdgcn_s_barrier();       // B(kt+1), P(kt+1) ready
    }
    {   // kt = 14: no further prefetch
        stage(15, 1);
        s16x8 af0[4], af1[4];
        read_af(0, af0); read_af(1, af1);
        asm volatile("s_waitcnt lgkmcnt(0)" ::: "memory");
        __builtin_amdgcn_sched_barrier(0);
        __builtin_amdgcn_s_barrier();
        mfma_kk(0, 0, af0);
        buildP(ca0, ca1, cb0, cb1, cbt);    // P(15)
        mfma_kk(0, 1, af1);
        asm volatile("s_waitcnt lgkmcnt(0)" ::: "memory");
        asm volatile("s_waitcnt vmcnt(0)" ::: "memory");
        __builtin_amdgcn_s_barrier();
    }
    {   // kt = 15: compute only
        s16x8 af0[4], af1[4];
        read_af(0, af0); read_af(1, af1);
        mfma_kk(1, 0, af0);
        mfma_kk(1, 1, af1);
    }

    // Z partials: reduce over the 8 threads sharing a row, plain stores.
    z0 += __shfl_xor(z0, 1); z0 += __shfl_xor(z0, 2); z0 += __shfl_xor(z0, 4);
    z1 += __shfl_xor(z1, 1); z1 += __shfl_xor(z1, 2); z1 += __shfl_xor(z1, 4);
    if ((t & 7) == 0) {
        Z4[(size_t)(ky * 2 + 0) * Bn + b0 + pb] = z0;
        Z4[(size_t)(ky * 2 + 1) * Bn + b0 + pb] = z1;
    }
    // U partials: private per-block slice, plain coalesced stores.
    float* Up = Upart + ((size_t)(ky * 2 + hw) * Bn + b0) * Fn;
    #pragma unroll
    for (int i = 0; i < 4; ++i)
        #pragma unroll
        for (int j = 0; j < 4; ++j)
            #pragma unroll
            for (int r = 0; r < 4; ++r) {
                const int row = i * 16 + (l >> 4) * 4 + r;
                const int col = n0 + j * 16 + (l & 15);
                Up[(size_t)row * Fn + col] = acc[i][j][r];
            }
}

// ---------------------------------------------------------------------------
// agg_bf16[h][b][f] = bf16( (sum_ky Upart[ky][h][b][f]) / (sum_ky Z4[ky][h][b]) )
__global__ __launch_bounds__(256) void k_agg(const float* __restrict__ Upart, const float* __restrict__ Z4,
                                             uint16_t* __restrict__ agg)
{
    const int gid = blockIdx.x * 256 + threadIdx.x;
    const int rb = gid >> 5;            // h*4096 + b
    const int h = rb >> 12, b = rb & 4095;
    const int f0 = (gid & 31) * 8;
    float zs = 0.f;
    #pragma unroll
    for (int ky = 0; ky < KY; ++ky) zs += Z4[(size_t)(ky * 2 + h) * Bn + b];
    const float zi = 1.0f / zs;
    f32x4 u0 = (f32x4){0.f,0.f,0.f,0.f}, u1 = (f32x4){0.f,0.f,0.f,0.f};
    #pragma unroll
    for (int ky = 0; ky < KY; ++ky) {
        const float* up = Upart + ((size_t)(ky * 2 + h) * Bn + b) * Fn + f0;
        u0 += *(const f32x4*)up;
        u1 += *(const f32x4*)(up + 4);
    }
    uint4 pk;
    pk.x = f2bf(u0[0] * zi) | ((uint32_t)f2bf(u0[1] * zi) << 16);
    pk.y = f2bf(u0[2] * zi) | ((uint32_t)f2bf(u0[3] * zi) << 16);
    pk.z = f2bf(u1[0] * zi) | ((uint32_t)f2bf(u1[1] * zi) << 16);
    pk.w = f2bf(u1[2] * zi) | ((uint32_t)f2bf(u1[3] * zi) << 16);
    *(uint4*)(agg + (size_t)rb * Fn + f0) = pk;
}

// ---------------------------------------------------------------------------
// enc[b][h*256+n] = relu([self | agg_h] @ enc_w[h]) , bf16 out.
__global__ __launch_bounds__(512) void k_enc(
    const uint16_t* __restrict__ self_bf, const uint16_t* __restrict__ agg,
    const uint16_t* __restrict__ enc_wT, uint16_t* __restrict__ enc)
{
    __shared__ uint16_t ldsA[128 * 64];
    __shared__ uint16_t ldsW[128 * 64];
    const int t = threadIdx.x, w = t >> 6, l = t & 63;
    const int b0 = blockIdx.x * 128;
    const int nblk = blockIdx.y * 128;
    const int h = blockIdx.z;
    const int wr = (w >> 2) * 64;
    const int wc = (w & 3) * 32;
    f32x4 acc[4][2];
    #pragma unroll
    for (int i = 0; i < 4; ++i)
        #pragma unroll
        for (int j = 0; j < 2; ++j)
            acc[i][j] = (f32x4){0.f, 0.f, 0.f, 0.f};

    const uint16_t* aggh = agg + (size_t)h * Bn * Fn;
    const char* Bsrc = (const char*)(enc_wT + (size_t)h * HIDn * 512);

    for (int kt = 0; kt < 8; ++kt) {
        const char* Ak = (const char*)((kt < 4) ? self_bf : aggh) + (kt & 3) * 128;
        #pragma unroll
        for (int i = 0; i < 2; ++i) {
            const uint32_t o = (uint32_t)(i * 8192 + t * 16);
            const uint32_t rr = o >> 7, kb = o & 127u;
            const uint4 da = *(const uint4*)(Ak + (size_t)(b0 + rr) * 512 + kb);
            *(uint4*)((char*)ldsA + swz(o)) = da;
            const uint4 db = *(const uint4*)(Bsrc + (size_t)(nblk + rr) * 1024 + kt * 128 + kb);
            *(uint4*)((char*)ldsW + swz(o)) = db;
        }
        __syncthreads();
        #pragma unroll
        for (int kk = 0; kk < 2; ++kk) {
            const uint32_t kb = (uint32_t)((kk * 32 + (l >> 4) * 8) * 2);
            s16x8 af[4], bw[2];
            #pragma unroll
            for (int i = 0; i < 4; ++i) {
                const uint32_t ar = (uint32_t)(wr + i * 16 + (l & 15));
                af[i] = *(const s16x8*)((const char*)ldsA + swz(ar * 128 + kb));
            }
            #pragma unroll
            for (int j = 0; j < 2; ++j) {
                const uint32_t br = (uint32_t)(wc + j * 16 + (l & 15));
                bw[j] = *(const s16x8*)((const char*)ldsW + swz(br * 128 + kb));
            }
            #pragma unroll
            for (int i = 0; i < 4; ++i)
                #pragma unroll
                for (int j = 0; j < 2; ++j)
                    acc[i][j] = __builtin_amdgcn_mfma_f32_16x16x32_bf16(af[i], bw[j], acc[i][j], 0, 0, 0);
        }
        __syncthreads();
    }
    #pragma unroll
    for (int i = 0; i < 4; ++i)
        #pragma unroll
        for (int j = 0; j < 2; ++j)
            #pragma unroll
            for (int r = 0; r < 4; ++r) {
                const int row = wr + i * 16 + (l >> 4) * 4 + r;
                const int col = nblk + wc + j * 16 + (l & 15);
                enc[(size_t)(b0 + row) * 512 + h * HIDn + col] = f2bf(fmaxf(acc[i][j][r], 0.f));
            }
}

// ---------------------------------------------------------------------------
// out[b][c] = enc @ out_w  (f32 out). Grid (64): 64 rows x 64 cols, K=512.
__global__ __launch_bounds__(256) void k_out(
    const uint16_t* __restrict__ enc, const uint16_t* __restrict__ out_wT, float* __restrict__ out)
{
    __shared__ uint16_t ldsA[64 * 64];
    __shared__ uint16_t ldsW[64 * 64];
    const int t = threadIdx.x, w = t >> 6, l = t & 63;
    const int b0 = blockIdx.x * 64;
    const int wr = w * 16;
    f32x4 acc[4];
    #pragma unroll
    for (int j = 0; j < 4; ++j) acc[j] = (f32x4){0.f, 0.f, 0.f, 0.f};

    for (int kt = 0; kt < 8; ++kt) {
        #pragma unroll
        for (int i = 0; i < 2; ++i) {
            const uint32_t o = (uint32_t)(i * 4096 + t * 16);
            const uint32_t rr = o >> 7, kb = o & 127u;
            const uint4 da = *(const uint4*)((const char*)enc + (size_t)(b0 + rr) * 1024 + kt * 128 + kb);
            *(uint4*)((char*)ldsA + swz(o)) = da;
            const uint4 db = *(const uint4*)((const char*)out_wT + (size_t)rr * 1024 + kt * 128 + kb);
            *(uint4*)((char*)ldsW + swz(o)) = db;
        }
        __syncthreads();
        #pragma unroll
        for (int kk = 0; kk < 2; ++kk) {
            const uint32_t kb = (uint32_t)((kk * 32 + (l >> 4) * 8) * 2);
            const uint32_t ar = (uint32_t)(wr + (l & 15));
            const s16x8 af = *(const s16x8*)((const char*)ldsA + swz(ar * 128 + kb));
            #pragma unroll
            for (int j = 0; j < 4; ++j) {
                const uint32_t br = (uint32_t)(j * 16 + (l & 15));
                const s16x8 bw = *(const s16x8*)((const char*)ldsW + swz(br * 128 + kb));
                acc[j] = __builtin_amdgcn_mfma_f32_16x16x32_bf16(af, bw, acc[j], 0, 0, 0);
            }
        }
        __syncthreads();
    }
    #pragma unroll
    for (int j = 0; j < 4; ++j)
        #pragma unroll
        for (int r = 0; r < 4; ++r) {
            const int row = wr + (l >> 4) * 4 + r;
            const int col = j * 16 + (l & 15);
            out[(size_t)(b0 + row) * Cn + col] = acc[j][r];
        }
}

// ---------------------------------------------------------------------------
extern "C" void kernel_launch(void* const* d_in, const int* in_sizes, int n_in,
                              void* d_out, int out_size, void* d_ws, size_t ws_size,
                              hipStream_t stream) {
    const float* self_feats = (const float*)d_in[0];
    const float* neigh      = (const float*)d_in[1];
    const float* mask       = (const float*)d_in[2];
    const float* a          = (const float*)d_in[3];
    const float* enc_w      = (const float*)d_in[4];
    const float* out_w      = (const float*)d_in[5];
    float* out = (float*)d_out;

    char* ws = (char*)d_ws;
    size_t off = 0;
    auto alloc = [&](size_t bytes) { char* p = ws + off; off += (bytes + 255) & ~(size_t)255; return p; };
    float*    Upart   = (float*)alloc((size_t)KY * 2 * Bn * Fn * 4); // 64 MB
    float*    Z4      = (float*)alloc((size_t)KY * 2 * Bn * 4);      // 256 KB
    float*    x       = (float*)alloc((size_t)2 * Bn * 4);
    float*    y       = (float*)alloc((size_t)2 * Mn * 4);
    char*     neighTg = (char*)alloc((size_t)Fn * Mn * 2);           // 4 MB, tiled+swizzled
    uint16_t* self_bf = (uint16_t*)alloc((size_t)Bn * Fn * 2);       // 2 MB
    uint16_t* agg_bf  = (uint16_t*)alloc((size_t)2 * Bn * Fn * 2);   // 4 MB
    uint16_t* enc     = (uint16_t*)alloc((size_t)Bn * 512 * 2);      // 4 MB
    uint16_t* enc_wT  = (uint16_t*)alloc((size_t)2 * HIDn * 512 * 2);
    uint16_t* out_wT  = (uint16_t*)alloc((size_t)Cn * 512 * 2);
    uint64_t* bitmask = (uint64_t*)alloc((size_t)Bn * Mn / 8);       // 4 MB

    k_prep_all<<<8320, 256, 0, stream>>>(self_feats, neigh, mask, a, enc_w, out_w,
                                         x, y, self_bf, neighTg, enc_wT, out_wT, bitmask);
    k_main<<<dim3(Bn / 64, KY), 512, 0, stream>>>((const uint8_t*)bitmask, x, y, neighTg, Upart, Z4);
    k_agg<<<(2 * Bn * Fn / 8) / 256, 256, 0, stream>>>(Upart, Z4, agg_bf);
    k_enc<<<dim3(Bn / 128, 2, 2), 512, 0, stream>>>(self_bf, agg_bf, enc_wT, enc);
    k_out<<<Bn / 64, 256, 0, stream>>>(enc, out_wT, out);
}

// Round 7
// 111.228 us; speedup vs baseline: 1.8534x; 1.8534x over previous
//
#include <hip/hip_runtime.h>
#include <stdint.h>

#define Bn 4096
#define Mn 8192
#define Fn 256
#define HIDn 256
#define Cn 64
#define KY 8            // K-split of M dimension (== #XCDs; one slice per XCD)
#define BM 128          // rows per block
#define MCH (Mn / KY)   // 1024 m per block
#define NIT (MCH / 64)  // 16 K-tiles per block

typedef float f32x4 __attribute__((ext_vector_type(4)));
typedef short s16x8 __attribute__((ext_vector_type(8)));

__device__ __forceinline__ uint16_t f2bf(float f) {
    union { float f; uint32_t u; } v; v.f = f;
    uint32_t r = v.u + 0x7FFFu + ((v.u >> 16) & 1u);
    return (uint16_t)(r >> 16);
}
__device__ __forceinline__ float bf2f(uint16_t u) {
    union { uint32_t u; float f; } v; v.u = (uint32_t)u << 16; return v.f;
}

// XOR swizzle for LDS tiles with 128B rows: flips bits 4-6 with row&7 (bits 7-9). Involution.
__device__ __forceinline__ uint32_t swz(uint32_t o) { return o ^ (((o >> 7) & 7u) << 4); }

__device__ __forceinline__ void glds16(const char* g, char* l) {
    __builtin_amdgcn_global_load_lds(
        (const __attribute__((address_space(1))) void*)g,
        (__attribute__((address_space(3))) void*)l, 16, 0, 0);
}

// ---------------------------------------------------------------------------
// Fused prep kernel, role-switched by blockIdx.x:
//  [0, 2048)    : maskpack via ballot -> 4 MB bitmask (coalesced loads AND stores)
//  [2048, 5120) : prep_xy — x[h][b], y[h][m], self_bf16
//  [5120, 7168) : tn — neighTg tiled+pre-swizzled bf16 transpose
//  [7168, 8320) : prep_w — enc_wT / out_wT bf16 transposes
__global__ __launch_bounds__(256) void k_prep_all(
    const float* __restrict__ selff, const float* __restrict__ neigh,
    const float* __restrict__ mask, const float* __restrict__ a,
    const float* __restrict__ enc_w, const float* __restrict__ out_w,
    float* __restrict__ x, float* __restrict__ y, uint16_t* __restrict__ self_bf,
    char* __restrict__ neighTg, uint16_t* __restrict__ enc_wT, uint16_t* __restrict__ out_wT,
    uint64_t* __restrict__ bitmask)
{
    __shared__ float tl[32][33];
    const int bid = blockIdx.x;
    if (bid < 2048) {
        // Each wave packs 4096 consecutive floats (16 KB contiguous).
        // iter i: lanes read 256B run, ballot -> u64 word i; lane i captures it.
        // One coalesced 512B store per wave at the end.
        const int wid = threadIdx.x >> 6, l = threadIdx.x & 63;
        const size_t base = ((size_t)bid * 4 + wid) * 4096;   // float index
        const float* mp = mask + base + l;
        uint64_t myq = 0;
        #pragma unroll 8
        for (int i = 0; i < 64; ++i) {
            const uint64_t q = __ballot(mp[i * 64] > 0.f);
            if (l == i) myq = q;
        }
        bitmask[base / 64 + l] = myq;
    } else if (bid < 5120) {
        const int w = threadIdx.x >> 6, l = threadIdx.x & 63;
        const int r = (bid - 2048) * 4 + w;           // 0..B+M-1
        const bool is_self = (r < Bn);
        const float* row = is_self ? (selff + (size_t)r * Fn) : (neigh + (size_t)(r - Bn) * Fn);
        const int aoff = is_self ? 0 : Fn;
        const float4 v  = *(const float4*)(row + l * 4);
        const float4 c0 = *(const float4*)(a + aoff + l * 4);
        const float4 c1 = *(const float4*)(a + 2 * Fn + aoff + l * 4);
        float d0 = v.x * c0.x + v.y * c0.y + v.z * c0.z + v.w * c0.w;
        float d1 = v.x * c1.x + v.y * c1.y + v.z * c1.z + v.w * c1.w;
        #pragma unroll
        for (int s = 32; s > 0; s >>= 1) { d0 += __shfl_xor(d0, s); d1 += __shfl_xor(d1, s); }
        if (is_self) {
            uint2 pk;
            pk.x = (uint32_t)f2bf(v.x) | ((uint32_t)f2bf(v.y) << 16);
            pk.y = (uint32_t)f2bf(v.z) | ((uint32_t)f2bf(v.w) << 16);
            *(uint2*)(self_bf + (size_t)r * Fn + l * 4) = pk;
            if (l == 0) { x[r] = d0; x[Bn + r] = d1; }
        } else {
            const int m = r - Bn;
            if (l == 0) { y[m] = d0; y[Mn + m] = d1; }
        }
    } else if (bid < 7168) {
        const int bid3 = bid - 5120;
        const int tx = threadIdx.x & 31, ty = threadIdx.x >> 5;
        const int m0 = (bid3 & 255) * 32, f0 = (bid3 >> 8) * 32;
        #pragma unroll
        for (int i = 0; i < 4; ++i)
            tl[ty + 8 * i][tx] = neigh[(size_t)(m0 + ty + 8 * i) * Fn + f0 + tx];
        __syncthreads();
        #pragma unroll
        for (int i = 0; i < 4; ++i) {
            const int f = f0 + ty + 8 * i;
            const int m = m0 + tx;
            const uint32_t o = (uint32_t)(f * 128 + (m & 63) * 2);
            *(uint16_t*)(neighTg + (size_t)(m >> 6) * 32768 + swz(o)) = f2bf(tl[tx][ty + 8 * i]);
        }
    } else {
        const int tid = (bid - 7168) * 256 + threadIdx.x;
        if (tid < 2 * HIDn * 512) {
            const int h = tid >> 17;
            const int rr = tid & 131071;
            const int n = rr >> 9, k = rr & 511;
            enc_wT[tid] = f2bf(enc_w[(size_t)h * 512 * HIDn + (size_t)k * HIDn + n]);
        } else {
            const int rr = tid - 2 * HIDn * 512;
            const int n = rr >> 9, k = rr & 511;
            out_wT[rr] = f2bf(out_w[(size_t)k * Cn + n]);
        }
    }
}

// ---------------------------------------------------------------------------
// Main fused kernel. 256 blocks 1-D; ky = bid&7 -> each XCD pinned to ONE
// ky-slice (round-robin dispatch) so neighTg slice + y slice stay L2-resident.
// BM=128 rows x full F=256 x both heads per block. LDS 136 KB, 1 block/CU.
// Double-buffered B (glds) AND P (ds_write) -> single barrier per K-tile.
__global__ __launch_bounds__(512, 2) void k_main(
    const uint8_t* __restrict__ bitb, const float* __restrict__ x, const float* __restrict__ y,
    const char* __restrict__ neighTg, uint16_t* __restrict__ Upart, float* __restrict__ Z4)
{
    __shared__ __align__(16) uint16_t ldsB[2][Fn * 64];       // 2 x 32KB, [f][m] swizzled
    __shared__ __align__(16) uint16_t ldsP[2][2 * BM * 64];   // 2 x 32KB, [h][row][m] swizzled
    __shared__ __align__(16) float ldsY[2 * MCH];             // 8KB
    const int t = threadIdx.x;
    const int w = t >> 6, l = t & 63;
    const int bid = blockIdx.x;
    const int ky = bid & 7;
    const int b0 = (bid >> 3) * BM;
    const int tile0 = ky * NIT;

    const int pb = t >> 2;            // P-build row (0..127), 4 threads/row
    const int pmf = (t & 3) * 16;     // 16 consecutive m's per thread
    const float x0 = x[b0 + pb];
    const float x1 = x[Bn + b0 + pb];
    float z0 = 0.f, z1 = 0.f;

    const int hw = w >> 2;            // head of this wave
    const int n0 = (w & 3) * 64;      // F-column block of this wave

    f32x4 acc[8][4];
    #pragma unroll
    for (int i = 0; i < 8; ++i)
        #pragma unroll
        for (int j = 0; j < 4; ++j)
            acc[i][j] = (f32x4){0.f, 0.f, 0.f, 0.f};

    const uint8_t* bp = bitb + (size_t)(b0 + pb) * (Mn / 8) + ky * (MCH / 8) + (t & 3) * 2;
    const uint32_t po0 = swz((uint32_t)(pb * 128 + (t & 3) * 32));
    const uint32_t po1 = po0 ^ 16u;   // +16B, no carry past bit 6
    const uint32_t gchunk = (uint32_t)(w * 4096);

    auto stage = [&](int kt, int buf) {
        const char* gb = neighTg + (size_t)(tile0 + kt) * 32768 + gchunk + (uint32_t)(l * 16);
        char* lb = (char*)ldsB[buf] + gchunk;
        #pragma unroll
        for (int c = 0; c < 4; ++c)
            glds16(gb + c * 1024, lb + c * 1024);
    };
    auto buildP = [&](int buf, int kt, uint32_t bits) {
        const float* Y0 = &ldsY[kt * 64 + pmf];
        const float* Y1 = &ldsY[MCH + kt * 64 + pmf];
        f32x4 ya[4], yb[4];
        #pragma unroll
        for (int q = 0; q < 4; ++q) { ya[q] = *(const f32x4*)(Y0 + q * 4); yb[q] = *(const f32x4*)(Y1 + q * 4); }
        uint16_t p0[16], p1[16];
        #pragma unroll
        for (int j = 0; j < 16; ++j) {
            const bool on = (bits >> j) & 1;
            float t0 = x0 + ya[j >> 2][j & 3];
            float s0 = fmaxf(t0, 0.2f * t0);
            float e0 = on ? __expf(s0) : 0.f;
            z0 += e0; p0[j] = f2bf(e0);
            float t1 = x1 + yb[j >> 2][j & 3];
            float s1 = fmaxf(t1, 0.2f * t1);
            float e1 = on ? __expf(s1) : 0.f;
            z1 += e1; p1[j] = f2bf(e1);
        }
        uint4 qa, qb;
        char* pw = (char*)ldsP[buf];
        qa.x = p0[0] | ((uint32_t)p0[1] << 16);  qa.y = p0[2] | ((uint32_t)p0[3] << 16);
        qa.z = p0[4] | ((uint32_t)p0[5] << 16);  qa.w = p0[6] | ((uint32_t)p0[7] << 16);
        qb.x = p0[8] | ((uint32_t)p0[9] << 16);  qb.y = p0[10] | ((uint32_t)p0[11] << 16);
        qb.z = p0[12] | ((uint32_t)p0[13] << 16); qb.w = p0[14] | ((uint32_t)p0[15] << 16);
        *(uint4*)(pw + po0) = qa;
        *(uint4*)(pw + po1) = qb;
        qa.x = p1[0] | ((uint32_t)p1[1] << 16);  qa.y = p1[2] | ((uint32_t)p1[3] << 16);
        qa.z = p1[4] | ((uint32_t)p1[5] << 16);  qa.w = p1[6] | ((uint32_t)p1[7] << 16);
        qb.x = p1[8] | ((uint32_t)p1[9] << 16);  qb.y = p1[10] | ((uint32_t)p1[11] << 16);
        qb.z = p1[12] | ((uint32_t)p1[13] << 16); qb.w = p1[14] | ((uint32_t)p1[15] << 16);
        *(uint4*)(pw + 16384 + po0) = qa;
        *(uint4*)(pw + 16384 + po1) = qb;
    };
    auto mfma_kk = [&](int buf, int kk) {
        const char* pA = (const char*)ldsP[buf] + hw * 16384;
        const char* pB = (const char*)ldsB[buf];
        const uint32_t kb = (uint32_t)((kk * 32 + (l >> 4) * 8) * 2);
        s16x8 af[8], bfr[4];
        #pragma unroll
        for (int i = 0; i < 8; ++i) {
            const uint32_t ar = (uint32_t)(i * 16 + (l & 15));
            af[i] = *(const s16x8*)(pA + swz(ar * 128 + kb));
        }
        #pragma unroll
        for (int j = 0; j < 4; ++j) {
            const uint32_t br = (uint32_t)(n0 + j * 16 + (l & 15));
            bfr[j] = *(const s16x8*)(pB + swz(br * 128 + kb));
        }
        __builtin_amdgcn_s_setprio(1);
        #pragma unroll
        for (int i = 0; i < 8; ++i)
            #pragma unroll
            for (int j = 0; j < 4; ++j)
                acc[i][j] = __builtin_amdgcn_mfma_f32_16x16x32_bf16(af[i], bfr[j], acc[i][j], 0, 0, 0);
        __builtin_amdgcn_s_setprio(0);
    };

    // ---- prologue: ldsY staged; bits(0),bits(1) loaded; B(0) staged; P(0) built
    {
        const int lin = t * 4;                       // 2048 floats total
        const int h = lin >> 10, mo = lin & 1023;
        *(float4*)&ldsY[lin] = *(const float4*)(y + (size_t)h * Mn + ky * MCH + mo);
    }
    uint32_t b_cur = *(const uint16_t*)(bp);
    uint32_t b_nxt = *(const uint16_t*)(bp + 8);
    stage(0, 0);
    __syncthreads();                                 // ldsY + B(0) ready (full drain)
    buildP(0, 0, b_cur);
    asm volatile("s_waitcnt lgkmcnt(0)" ::: "memory");
    __builtin_amdgcn_s_barrier();                    // P(0) ready

    // ---- main loop: one barrier per K-tile
    for (int kt = 0; kt < NIT - 1; ++kt) {
        const int cur = kt & 1, nxt = cur ^ 1;
        stage(kt + 1, nxt);                          // 4 glds -> B[nxt]
        const int ktf = (kt + 2 < NIT) ? (kt + 2) : (NIT - 1);
        const uint32_t b_fut = *(const uint16_t*)(bp + ktf * 8);   // 1 vmem, stays in flight
        mfma_kk(cur, 0);
        buildP(nxt, kt + 1, b_nxt);                  // P[nxt]; ds ops only
        mfma_kk(cur, 1);
        b_nxt = b_fut;
        asm volatile("s_waitcnt lgkmcnt(0)" ::: "memory");  // my P writes done
        asm volatile("s_waitcnt vmcnt(1)" ::: "memory");    // glds drained; u16 may fly
        __builtin_amdgcn_s_barrier();                // B[nxt], P[nxt] ready for all
    }
    mfma_kk((NIT - 1) & 1, 0);
    mfma_kk((NIT - 1) & 1, 1);

    // Z partials: reduce over the 4 threads sharing a row, plain stores.
    z0 += __shfl_xor(z0, 1); z0 += __shfl_xor(z0, 2);
    z1 += __shfl_xor(z1, 1); z1 += __shfl_xor(z1, 2);
    if ((t & 3) == 0) {
        Z4[(size_t)(ky * 2 + 0) * Bn + b0 + pb] = z0;
        Z4[(size_t)(ky * 2 + 1) * Bn + b0 + pb] = z1;
    }
    // U partials: private per-(ky,head) slice, bf16 stores.
    uint16_t* Up = Upart + ((size_t)(ky * 2 + hw) * Bn + b0) * Fn;
    #pragma unroll
    for (int i = 0; i < 8; ++i)
        #pragma unroll
        for (int j = 0; j < 4; ++j)
            #pragma unroll
            for (int r = 0; r < 4; ++r) {
                const int row = i * 16 + (l >> 4) * 4 + r;
                const int col = n0 + j * 16 + (l & 15);
                Up[(size_t)row * Fn + col] = f2bf(acc[i][j][r]);
            }
}

// ---------------------------------------------------------------------------
// agg_bf16[h][b][f] = bf16( (sum_ky Upart[ky][h][b][f]) / (sum_ky Z4[ky][h][b]) )
__global__ __launch_bounds__(256) void k_agg(const uint16_t* __restrict__ Upart, const float* __restrict__ Z4,
                                             uint16_t* __restrict__ agg)
{
    const int gid = blockIdx.x * 256 + threadIdx.x;
    const int rb = gid >> 5;            // h*4096 + b
    const int h = rb >> 12, b = rb & 4095;
    const int f0 = (gid & 31) * 8;
    float zs = 0.f;
    #pragma unroll
    for (int ky = 0; ky < KY; ++ky) zs += Z4[(size_t)(ky * 2 + h) * Bn + b];
    const float zi = 1.0f / zs;
    float u[8] = {0.f, 0.f, 0.f, 0.f, 0.f, 0.f, 0.f, 0.f};
    #pragma unroll
    for (int ky = 0; ky < KY; ++ky) {
        const uint16_t* up = Upart + ((size_t)(ky * 2 + h) * Bn + b) * Fn + f0;
        const uint4 raw = *(const uint4*)up;
        const uint32_t rr[4] = {raw.x, raw.y, raw.z, raw.w};
        #pragma unroll
        for (int q = 0; q < 4; ++q) {
            u[q * 2 + 0] += bf2f((uint16_t)(rr[q] & 0xFFFFu));
            u[q * 2 + 1] += bf2f((uint16_t)(rr[q] >> 16));
        }
    }
    uint4 pk;
    pk.x = f2bf(u[0] * zi) | ((uint32_t)f2bf(u[1] * zi) << 16);
    pk.y = f2bf(u[2] * zi) | ((uint32_t)f2bf(u[3] * zi) << 16);
    pk.z = f2bf(u[4] * zi) | ((uint32_t)f2bf(u[5] * zi) << 16);
    pk.w = f2bf(u[6] * zi) | ((uint32_t)f2bf(u[7] * zi) << 16);
    *(uint4*)(agg + (size_t)rb * Fn + f0) = pk;
}

// ---------------------------------------------------------------------------
// enc[b][h*256+n] = relu([self | agg_h] @ enc_w[h]) , bf16 out.
__global__ __launch_bounds__(512) void k_enc(
    const uint16_t* __restrict__ self_bf, const uint16_t* __restrict__ agg,
    const uint16_t* __restrict__ enc_wT, uint16_t* __restrict__ enc)
{
    __shared__ uint16_t ldsA[128 * 64];
    __shared__ uint16_t ldsW[128 * 64];
    const int t = threadIdx.x, w = t >> 6, l = t & 63;
    const int b0 = blockIdx.x * 128;
    const int nblk = blockIdx.y * 128;
    const int h = blockIdx.z;
    const int wr = (w >> 2) * 64;
    const int wc = (w & 3) * 32;
    f32x4 acc[4][2];
    #pragma unroll
    for (int i = 0; i < 4; ++i)
        #pragma unroll
        for (int j = 0; j < 2; ++j)
            acc[i][j] = (f32x4){0.f, 0.f, 0.f, 0.f};

    const uint16_t* aggh = agg + (size_t)h * Bn * Fn;
    const char* Bsrc = (const char*)(enc_wT + (size_t)h * HIDn * 512);

    for (int kt = 0; kt < 8; ++kt) {
        const char* Ak = (const char*)((kt < 4) ? self_bf : aggh) + (kt & 3) * 128;
        #pragma unroll
        for (int i = 0; i < 2; ++i) {
            const uint32_t o = (uint32_t)(i * 8192 + t * 16);
            const uint32_t rr = o >> 7, kb = o & 127u;
            const uint4 da = *(const uint4*)(Ak + (size_t)(b0 + rr) * 512 + kb);
            *(uint4*)((char*)ldsA + swz(o)) = da;
            const uint4 db = *(const uint4*)(Bsrc + (size_t)(nblk + rr) * 1024 + kt * 128 + kb);
            *(uint4*)((char*)ldsW + swz(o)) = db;
        }
        __syncthreads();
        #pragma unroll
        for (int kk = 0; kk < 2; ++kk) {
            const uint32_t kb = (uint32_t)((kk * 32 + (l >> 4) * 8) * 2);
            s16x8 af[4], bw[2];
            #pragma unroll
            for (int i = 0; i < 4; ++i) {
                const uint32_t ar = (uint32_t)(wr + i * 16 + (l & 15));
                af[i] = *(const s16x8*)((const char*)ldsA + swz(ar * 128 + kb));
            }
            #pragma unroll
            for (int j = 0; j < 2; ++j) {
                const uint32_t br = (uint32_t)(wc + j * 16 + (l & 15));
                bw[j] = *(const s16x8*)((const char*)ldsW + swz(br * 128 + kb));
            }
            #pragma unroll
            for (int i = 0; i < 4; ++i)
                #pragma unroll
                for (int j = 0; j < 2; ++j)
                    acc[i][j] = __builtin_amdgcn_mfma_f32_16x16x32_bf16(af[i], bw[j], acc[i][j], 0, 0, 0);
        }
        __syncthreads();
    }
    #pragma unroll
    for (int i = 0; i < 4; ++i)
        #pragma unroll
        for (int j = 0; j < 2; ++j)
            #pragma unroll
            for (int r = 0; r < 4; ++r) {
                const int row = wr + i * 16 + (l >> 4) * 4 + r;
                const int col = nblk + wc + j * 16 + (l & 15);
                enc[(size_t)(b0 + row) * 512 + h * HIDn + col] = f2bf(fmaxf(acc[i][j][r], 0.f));
            }
}

// ---------------------------------------------------------------------------
// out[b][c] = enc @ out_w  (f32 out). Grid (64): 64 rows x 64 cols, K=512.
__global__ __launch_bounds__(256) void k_out(
    const uint16_t* __restrict__ enc, const uint16_t* __restrict__ out_wT, float* __restrict__ out)
{
    __shared__ uint16_t ldsA[64 * 64];
    __shared__ uint16_t ldsW[64 * 64];
    const int t = threadIdx.x, w = t >> 6, l = t & 63;
    const int b0 = blockIdx.x * 64;
    const int wr = w * 16;
    f32x4 acc[4];
    #pragma unroll
    for (int j = 0; j < 4; ++j) acc[j] = (f32x4){0.f, 0.f, 0.f, 0.f};

    for (int kt = 0; kt < 8; ++kt) {
        #pragma unroll
        for (int i = 0; i < 2; ++i) {
            const uint32_t o = (uint32_t)(i * 4096 + t * 16);
            const uint32_t rr = o >> 7, kb = o & 127u;
            const uint4 da = *(const uint4*)((const char*)enc + (size_t)(b0 + rr) * 1024 + kt * 128 + kb);
            *(uint4*)((char*)ldsA + swz(o)) = da;
            const uint4 db = *(const uint4*)((const char*)out_wT + (size_t)rr * 1024 + kt * 128 + kb);
            *(uint4*)((char*)ldsW + swz(o)) = db;
        }
        __syncthreads();
        #pragma unroll
        for (int kk = 0; kk < 2; ++kk) {
            const uint32_t kb = (uint32_t)((kk * 32 + (l >> 4) * 8) * 2);
            const uint32_t ar = (uint32_t)(wr + (l & 15));
            const s16x8 af = *(const s16x8*)((const char*)ldsA + swz(ar * 128 + kb));
            #pragma unroll
            for (int j = 0; j < 4; ++j) {
                const uint32_t br = (uint32_t)(j * 16 + (l & 15));
                const s16x8 bw = *(const s16x8*)((const char*)ldsW + swz(br * 128 + kb));
                acc[j] = __builtin_amdgcn_mfma_f32_16x16x32_bf16(af, bw, acc[j], 0, 0, 0);
            }
        }
        __syncthreads();
    }
    #pragma unroll
    for (int j = 0; j < 4; ++j)
        #pragma unroll
        for (int r = 0; r < 4; ++r) {
            const int row = wr + (l >> 4) * 4 + r;
            const int col = j * 16 + (l & 15);
            out[(size_t)(b0 + row) * Cn + col] = acc[j][r];
        }
}

// ---------------------------------------------------------------------------
extern "C" void kernel_launch(void* const* d_in, const int* in_sizes, int n_in,
                              void* d_out, int out_size, void* d_ws, size_t ws_size,
                              hipStream_t stream) {
    const float* self_feats = (const float*)d_in[0];
    const float* neigh      = (const float*)d_in[1];
    const float* mask       = (const float*)d_in[2];
    const float* a          = (const float*)d_in[3];
    const float* enc_w      = (const float*)d_in[4];
    const float* out_w      = (const float*)d_in[5];
    float* out = (float*)d_out;

    char* ws = (char*)d_ws;
    size_t off = 0;
    auto alloc = [&](size_t bytes) { char* p = ws + off; off += (bytes + 255) & ~(size_t)255; return p; };
    uint16_t* Upart   = (uint16_t*)alloc((size_t)KY * 2 * Bn * Fn * 2); // 32 MB bf16
    float*    Z4      = (float*)alloc((size_t)KY * 2 * Bn * 4);         // 256 KB
    float*    x       = (float*)alloc((size_t)2 * Bn * 4);
    float*    y       = (float*)alloc((size_t)2 * Mn * 4);
    char*     neighTg = (char*)alloc((size_t)Fn * Mn * 2);              // 4 MB, tiled+swizzled
    uint16_t* self_bf = (uint16_t*)alloc((size_t)Bn * Fn * 2);          // 2 MB
    uint16_t* agg_bf  = (uint16_t*)alloc((size_t)2 * Bn * Fn * 2);      // 4 MB
    uint16_t* enc     = (uint16_t*)alloc((size_t)Bn * 512 * 2);         // 4 MB
    uint16_t* enc_wT  = (uint16_t*)alloc((size_t)2 * HIDn * 512 * 2);
    uint16_t* out_wT  = (uint16_t*)alloc((size_t)Cn * 512 * 2);
    uint64_t* bitmask = (uint64_t*)alloc((size_t)Bn * Mn / 8);          // 4 MB

    k_prep_all<<<8320, 256, 0, stream>>>(self_feats, neigh, mask, a, enc_w, out_w,
                                         x, y, self_bf, neighTg, enc_wT, out_wT, bitmask);
    k_main<<<256, 512, 0, stream>>>((const uint8_t*)bitmask, x, y, neighTg, Upart, Z4);
    k_agg<<<(2 * Bn * Fn / 8) / 256, 256, 0, stream>>>(Upart, Z4, agg_bf);
    k_enc<<<dim3(Bn / 128, 2, 2), 512, 0, stream>>>(self_bf, agg_bf, enc_wT, enc);
    k_out<<<Bn / 64, 256, 0, stream>>>(enc, out_wT, out);
}